// Round 7
// baseline (1678.247 us; speedup 1.0000x reference)
//
#include <hip/hip_runtime.h>
#include <math.h>

#define NN   20000
#define EE   80000
#define ELP  100000   // EE + NN self loops
#define NGR  64
#define EMB  780
#define W3   2340
#define EMBP 832      // 780 padded to mult of 64 (BK)
#define W3P  2368     // 2340 padded to mult of 64

static inline int cdiv_i(long long a, long long b){ return (int)((a + b - 1) / b); }

typedef _Float16 f16;
typedef _Float16 f16x4 __attribute__((ext_vector_type(4)));
typedef _Float16 f16x8 __attribute__((ext_vector_type(8)));
typedef float    f32x4 __attribute__((ext_vector_type(4)));

__device__ __forceinline__ void async_ld16(const f16* g, f16* l){
    __builtin_amdgcn_global_load_lds(
        (const __attribute__((address_space(1))) unsigned int*)g,
        (__attribute__((address_space(3))) unsigned int*)l,
        16, 0, 0);
}

// ---------------- utility kernels ----------------
__global__ void k_zero_f32(float* p, int n){
    int i = blockIdx.x*256 + threadIdx.x; if (i < n) p[i] = 0.f;
}
__global__ void k_zero_i32(int* p, int n){
    int i = blockIdx.x*256 + threadIdx.x; if (i < n) p[i] = 0;
}
__global__ void k_copy_i32(const int* __restrict__ s, int* __restrict__ d, int n){
    int i = blockIdx.x*256 + threadIdx.x; if (i < n) d[i] = s[i];
}

// W [K,N] fp32 -> Wt [N,KP] f16, optional per-k scale (BN fold), pad k zeroed
__global__ void k_transpose(const float* __restrict__ W, f16* __restrict__ Wt,
                            const float* __restrict__ sc, int K, int N, int KP){
    __shared__ float T[32][33];
    int n0 = blockIdx.x*32, k0 = blockIdx.y*32;
    int tx = threadIdx.x, ty = threadIdx.y;   // 32 x 8
#pragma unroll
    for (int r = 0; r < 4; r++){
        int k = k0 + ty + r*8;
        float v = 0.f;
        if (k < K && n0 + tx < N){
            v = W[(size_t)k*N + n0 + tx];
            if (sc) v *= sc[k];
        }
        T[ty + r*8][tx] = v;
    }
    __syncthreads();
#pragma unroll
    for (int r = 0; r < 4; r++){
        int n = n0 + ty + r*8;
        int k = k0 + tx;
        if (n < N && k < KP) Wt[(size_t)n*KP + k] = (f16)T[tx][ty + r*8];
    }
}

// dvec[n] += sum_{k in slice} sh[k] * W[k,n]  — coalesced, K split across blockIdx.y
#define DVEC_KSPLIT 32
__global__ void k_dvec(const float* __restrict__ W, const float* __restrict__ sh,
                       float* __restrict__ dvec, int K, int N){
    int n = blockIdx.x*256 + threadIdx.x;
    if (n >= N) return;
    int slice = blockIdx.y;
    int k0 = (int)(((long long)K * slice) / DVEC_KSPLIT);
    int k1 = (int)(((long long)K * (slice+1)) / DVEC_KSPLIT);
    float s = 0.f;
    for (int k = k0; k < k1; k++) s += sh[k] * W[(size_t)k*N + n];
    atomicAdd(&dvec[n], s);
}

// ---------------- h0 ----------------
__global__ void k_build_h(const float* __restrict__ x, const float* __restrict__ tW,
                          const float* __restrict__ tb, f16* __restrict__ h){
    int idx = blockIdx.x*256 + threadIdx.x;
    if (idx >= NN*EMBP) return;
    int n = idx / EMBP, c = idx - n*EMBP;
    const float* xr = x + (size_t)n*772;
    float v;
    if (c < 768) v = xr[c];
    else if (c < EMB){
        int j = c - 768;
        v = tb[j] + xr[768]*tW[j] + xr[769]*tW[12+j] + xr[770]*tW[24+j] + xr[771]*tW[36+j];
    } else v = 0.f;
    h[idx] = (f16)v;
}

// ---------------- CSR build ----------------
__global__ void k_deg(const int* __restrict__ ei, int* __restrict__ deg){
    int k = blockIdx.x*256 + threadIdx.x; if (k >= ELP) return;
    int d = (k < EE) ? ei[EE + k] : (k - EE);
    atomicAdd(&deg[d], 1);
}

// 20 nodes/thread local sum -> single 1024-scan -> write prefixes
__global__ __launch_bounds__(1024) void k_scan(const int* __restrict__ deg, int* __restrict__ rp){
    __shared__ int part[1024];
    int tid = threadIdx.x;
    int i0 = tid*20;
    int n = (i0 < NN) ? min(20, NN - i0) : 0;
    int s = 0;
    for (int k = 0; k < n; k++) s += deg[i0+k];
    part[tid] = s; __syncthreads();
    for (int off = 1; off < 1024; off <<= 1){
        int t = (tid >= off) ? part[tid-off] : 0;
        __syncthreads();
        part[tid] += t;
        __syncthreads();
    }
    int run = part[tid] - s;   // exclusive prefix
    for (int k = 0; k < n; k++){ rp[i0+k] = run; run += deg[i0+k]; }
    if (tid == 1023) rp[NN] = part[1023];
}

__global__ void k_fill(const int* __restrict__ ei, int* __restrict__ cursor, int* __restrict__ csrc){
    int k = blockIdx.x*256 + threadIdx.x; if (k >= ELP) return;
    int s, d;
    if (k < EE){ s = ei[k]; d = ei[EE + k]; } else { s = k - EE; d = s; }
    int pos = atomicAdd(&cursor[d], 1);
    csrc[pos] = s;
}

// graph ranges from sorted batch
__global__ void k_grp(const int* __restrict__ batch, int* __restrict__ grp){
    int g = blockIdx.x*256 + threadIdx.x; if (g > NGR) return;
    int lo = 0, hi = NN;
    while (lo < hi){ int mid = (lo+hi)>>1; if (batch[mid] < g) lo = mid+1; else hi = mid; }
    grp[g] = lo;
}

// ------ MFMA f16 GEMM, XCD-pinned strips, BK=64 (two 32-K panels per barrier pair) ------
__global__ __launch_bounds__(256) void k_gemm_mfma(const f16* __restrict__ A,
                                                   const f16* __restrict__ Bt,
                                                   const float* __restrict__ dvec,
                                                   f16* __restrict__ C,
                                                   int M, int N, int KP, int SN,
                                                   int Mtiles, int NT){
    int bid = blockIdx.x;
    int xcd = bid & 7;
    int j   = bid >> 3;
    int sl  = j / NT;
    int nt  = j - sl*NT;
    int mt  = sl*8 + xcd;
    if (mt >= Mtiles) return;
    int m0 = mt*128, n0 = nt*128;

    __shared__ f16 As[128*64];   // two 128x32 panels
    __shared__ f16 Bs[128*64];
    int tid = threadIdx.x;
    int w = tid >> 6, lane = tid & 63;

    int lrow = lane >> 2;
    int lko  = (lane & 3) * 8;

    int i2a = w*2, i2b = w*2 + 1;
    const f16* gA0 = A  + (size_t)min(m0 + i2a*16 + lrow, M-1)*KP + lko;
    const f16* gA1 = A  + (size_t)min(m0 + i2b*16 + lrow, M-1)*KP + lko;
    const f16* gB0 = Bt + (size_t)min(n0 + i2a*16 + lrow, N-1)*KP + lko;
    const f16* gB1 = Bt + (size_t)min(n0 + i2b*16 + lrow, N-1)*KP + lko;
    f16* lA0 = &As[i2a*512]; f16* lA1 = &As[i2b*512];
    f16* lB0 = &Bs[i2a*512]; f16* lB1 = &Bs[i2b*512];

    f32x4 acc[4][4];
#pragma unroll
    for (int i = 0; i < 4; i++)
#pragma unroll
        for (int j2 = 0; j2 < 4; j2++) acc[i][j2] = (f32x4)0.f;

    int wm = (w & 1) * 64, wn = (w >> 1) * 64;
    int lq = lane >> 4, lm = lane & 15;

    for (int kk = 0; kk < KP; kk += 64){
        __syncthreads();
        async_ld16(gA0 + kk, lA0);
        async_ld16(gA1 + kk, lA1);
        async_ld16(gB0 + kk, lB0);
        async_ld16(gB1 + kk, lB1);
        async_ld16(gA0 + kk + 32, lA0 + 4096);
        async_ld16(gA1 + kk + 32, lA1 + 4096);
        async_ld16(gB0 + kk + 32, lB0 + 4096);
        async_ld16(gB1 + kk + 32, lB1 + 4096);
        __syncthreads();

#pragma unroll
        for (int half = 0; half < 2; half++){
            const f16* Ap = As + half*4096;
            const f16* Bp = Bs + half*4096;
            f16x8 aF[4], bF[4];
#pragma unroll
            for (int mi = 0; mi < 4; mi++)
                aF[mi] = *(const f16x8*)&Ap[(wm + mi*16 + lm)*32 + lq*8];
#pragma unroll
            for (int ni = 0; ni < 4; ni++)
                bF[ni] = *(const f16x8*)&Bp[(wn + ni*16 + lm)*32 + lq*8];
#pragma unroll
            for (int mi = 0; mi < 4; mi++)
#pragma unroll
                for (int ni = 0; ni < 4; ni++)
                    acc[mi][ni] = __builtin_amdgcn_mfma_f32_16x16x32_f16(aF[mi], bF[ni], acc[mi][ni], 0, 0, 0);
        }
    }

#pragma unroll
    for (int mi = 0; mi < 4; mi++){
#pragma unroll
        for (int ni = 0; ni < 4; ni++){
            int col = n0 + wn + ni*16 + lm;
            if (col < SN){
                float dv = (col < N) ? dvec[col] : 0.f;
                int rbase = m0 + wm + mi*16 + lq*4;
#pragma unroll
                for (int r = 0; r < 4; r++){
                    int row = rbase + r;
                    if (row < M){
                        float v = (col < N) ? (acc[mi][ni][r] + dv) : 0.f;
                        C[(size_t)row*SN + col] = (f16)v;
                    }
                }
            }
        }
    }
}

// ---------------- attention coefficients (f16x4 loads) ----------------
__global__ void k_att(const f16* __restrict__ hp, const float* __restrict__ asrc,
                      const float* __restrict__ adst, float* __restrict__ a_s,
                      float* __restrict__ a_d, int H, int SP){
    int n = blockIdx.x;
    int wv = threadIdx.x >> 6, lane = threadIdx.x & 63;
    const f16* row = hp + (size_t)n*SP + wv*EMB;
    const float* pa = asrc + wv*EMB;
    const float* pd = adst + wv*EMB;
    float s = 0.f, d = 0.f;
    for (int c = lane*4; c < EMB; c += 256){
        f16x4 v = *(const f16x4*)(row + c);
#pragma unroll
        for (int jj = 0; jj < 4; jj++){
            float f = (float)v[jj];
            s += f*pa[c+jj]; d += f*pd[c+jj];
        }
    }
#pragma unroll
    for (int off = 32; off; off >>= 1){ s += __shfl_xor(s, off); d += __shfl_xor(d, off); }
    if (lane == 0){ a_s[n*H + wv] = s; a_d[n*H + wv] = d; }
}

// ---- per-dst softmax + aggregation + bias + tanh: barrier-free, LDS-free, f16x8 ----
// Each of the 4 waves redundantly computes the node softmax via shuffle reductions
// (lanes = edges), then gathers with per-edge __shfl broadcast of src/alpha.
template<int H>
__global__ __launch_bounds__(256) void k_agg2(const f16* __restrict__ hp, const int* __restrict__ rp,
                                              const int* __restrict__ csrc, const float* __restrict__ a_s,
                                              const float* __restrict__ a_d, const float* __restrict__ bias,
                                              f16* __restrict__ y, int SP, int W){
    int n = blockIdx.x, tid = threadIdx.x, lane = tid & 63;
    int beg = rp[n], deg = rp[n+1] - beg;

    float adv[H];
#pragma unroll
    for (int h = 0; h < H; h++) adv[h] = a_d[n*H + h];

    // pass 1: max over incoming edges (leaky-relu'd logits)
    float mx[H];
#pragma unroll
    for (int h = 0; h < H; h++) mx[h] = -1e30f;
    for (int base = 0; base < deg; base += 64){
        int e = base + lane;
        if (e < deg){
            int s = csrc[beg + e];
#pragma unroll
            for (int h = 0; h < H; h++){
                float t = a_s[s*H + h] + adv[h];
                t = t > 0.f ? t : 0.2f*t;
                mx[h] = fmaxf(mx[h], t);
            }
        }
    }
#pragma unroll
    for (int off = 32; off; off >>= 1)
#pragma unroll
        for (int h = 0; h < H; h++) mx[h] = fmaxf(mx[h], __shfl_xor(mx[h], off));

    // pass 2: denom
    float dn[H];
#pragma unroll
    for (int h = 0; h < H; h++) dn[h] = 0.f;
    for (int base = 0; base < deg; base += 64){
        int e = base + lane;
        if (e < deg){
            int s = csrc[beg + e];
#pragma unroll
            for (int h = 0; h < H; h++){
                float t = a_s[s*H + h] + adv[h];
                t = t > 0.f ? t : 0.2f*t;
                dn[h] += expf(t - mx[h]);
            }
        }
    }
#pragma unroll
    for (int off = 32; off; off >>= 1)
#pragma unroll
        for (int h = 0; h < H; h++) dn[h] += __shfl_xor(dn[h], off);
    float inv[H];
#pragma unroll
    for (int h = 0; h < H; h++) inv[h] = 1.f / (dn[h] + 1e-16f);

    // column groups: c = 2048*g + tid*8 ; head-split for f16x8 straddling a head boundary
    float acc[2][8];
#pragma unroll
    for (int g = 0; g < 2; g++)
#pragma unroll
        for (int j = 0; j < 8; j++) acc[g][j] = 0.f;
    int  cg[2];  cg[0] = tid*8; cg[1] = 2048 + tid*8;
    bool act[2]; act[0] = cg[0] < W; act[1] = cg[1] < W;
    int hlo[2], hhi[2], nsp[2];
#pragma unroll
    for (int g = 0; g < 2; g++){
        int c = cg[g];
        int hl = min(c / EMB, H-1);
        int hh = min((c+7) / EMB, H-1);
        hlo[g] = hl; hhi[g] = hh;
        nsp[g] = (hh > hl) ? (EMB*(hl+1) - c) : 8;
    }

    // main gather loop (chunked for deg>64; typical: one chunk)
    for (int base = 0; base < deg; base += 64){
        int cnt = min(64, deg - base);
        int sl = 0; float al[H];
        {
            int e = base + lane;
            if (e < deg){
                sl = csrc[beg + e];
#pragma unroll
                for (int h = 0; h < H; h++){
                    float t = a_s[sl*H + h] + adv[h];
                    t = t > 0.f ? t : 0.2f*t;
                    al[h] = expf(t - mx[h]) * inv[h];
                }
            } else {
#pragma unroll
                for (int h = 0; h < H; h++) al[h] = 0.f;
            }
        }
#pragma unroll 2
        for (int e = 0; e < cnt; e++){
            int s = __shfl(sl, e);
            float a0 = __shfl(al[0], e);
            float a1 = (H==3) ? __shfl(al[1], e) : a0;
            float a2 = (H==3) ? __shfl(al[2], e) : a0;
            const f16* row = hp + (size_t)s*SP;
#pragma unroll
            for (int g = 0; g < 2; g++){
                if (act[g]){
                    f16x8 v = *(const f16x8*)(row + cg[g]);
                    float lo = (hlo[g]==0) ? a0 : (hlo[g]==1 ? a1 : a2);
                    float hi = (hhi[g]==0) ? a0 : (hhi[g]==1 ? a1 : a2);
#pragma unroll
                    for (int j = 0; j < 8; j++){
                        float alj = (j < nsp[g]) ? lo : hi;
                        acc[g][j] += alj * (float)v[j];
                    }
                }
            }
        }
    }

    // epilogue: bias + tanh + write (pad cols -> 0)
#pragma unroll
    for (int g = 0; g < 2; g++){
        int c = cg[g];
        if (c < SP){
            f16x8 o;
#pragma unroll
            for (int j = 0; j < 8; j++){
                float vv = (c + j < W) ? tanhf(acc[g][j] + bias[c+j]) : 0.f;
                o[j] = (f16)vv;
            }
            *(f16x8*)(y + (size_t)n*SP + c) = o;
        }
    }
}

// ---------------- BatchNorm stats: partial sums per slice (no atomics) ----------------
__global__ void k_bnstat(const f16* __restrict__ y, float* __restrict__ ps,
                         float* __restrict__ pq, int W, int SP){
    int c0 = (blockIdx.x*256 + threadIdx.x)*4;
    if (c0 >= W) return;
    int slice = blockIdx.y;   // 0..63
    float s[4] = {0,0,0,0}, q[4] = {0,0,0,0};
    for (int r = slice; r < NN; r += 64){
        f16x4 u = *(const f16x4*)(y + (size_t)r*SP + c0);
#pragma unroll
        for (int j = 0; j < 4; j++){ float v = (float)u[j]; s[j] += v; q[j] += v*v; }
    }
#pragma unroll
    for (int j = 0; j < 4; j++){
        ps[(size_t)slice*W3 + c0+j] = s[j];
        pq[(size_t)slice*W3 + c0+j] = q[j];
    }
}

// reduce partials; sc = istd*gamma, sh = beta - mu*istd*gamma
__global__ void k_bnfin(const float* __restrict__ ps, const float* __restrict__ pq,
                        const float* __restrict__ gamma, const float* __restrict__ beta,
                        float* __restrict__ sc, float* __restrict__ sh, int W){
    int c = blockIdx.x*256 + threadIdx.x; if (c >= W) return;
    float m = 0.f, q = 0.f;
    for (int s = 0; s < 64; s++){ m += ps[(size_t)s*W3 + c]; q += pq[(size_t)s*W3 + c]; }
    m *= (1.f/NN);
    float v = q * (1.f/NN) - m*m;
    float is = 1.f / sqrtf(v + 1e-5f);
    float g = gamma[c];
    sc[c] = is * g;
    sh[c] = beta[c] - m * is * g;
}

// ---------------- segmented pooling (raw y; BN folded into MLP) ----------------
__global__ void k_pool(const f16* __restrict__ h, const int* __restrict__ grp,
                       float* __restrict__ pooled){
    int g = blockIdx.x;
    int c = threadIdx.x*4;
    if (c >= EMB) return;
    int r0 = grp[g], r1 = grp[g+1];
    float s0=0.f, s1=0.f, s2=0.f, s3=0.f;
    for (int r = r0; r < r1; r++){
        f16x4 u = *(const f16x4*)(h + (size_t)r*EMBP + c);
        s0 += (float)u[0]; s1 += (float)u[1]; s2 += (float)u[2]; s3 += (float)u[3];
    }
    pooled[g*EMB + c] = s0; pooled[g*EMB + c+1] = s1;
    pooled[g*EMB + c+2] = s2; pooled[g*EMB + c+3] = s3;
}

__global__ __launch_bounds__(256) void k_mlp(const float* __restrict__ pooled, const int* __restrict__ grp,
                                             const float* __restrict__ sc, const float* __restrict__ sh,
                                             const float* __restrict__ W1, const float* __restrict__ b1,
                                             const float* __restrict__ W2, const float* __restrict__ b2,
                                             float* __restrict__ out){
    __shared__ float p[EMB];
    __shared__ float hid[128];
    int g = blockIdx.x, tid = threadIdx.x;
    int cnt = grp[g+1] - grp[g];
    float ic = 1.f / fmaxf((float)cnt, 1.f);
    for (int c = tid; c < EMB; c += 256){
        float v = pooled[g*EMB + c] * ic * sc[c] + sh[c];   // BN(mean) — affine commutes with mean
        p[c] = v > 0.f ? v : 0.f;
    }
    __syncthreads();
    if (tid < 128){
        float s = b1[tid];
        for (int k = 0; k < EMB; k++) s += p[k] * W1[k*128 + tid];
        hid[tid] = tanhf(s);
    }
    __syncthreads();
    if (tid < 64){
        float s = b2[tid];
        for (int k = 0; k < 128; k++) s += hid[k] * W2[k*64 + tid];
        out[g*64 + tid] = s;
    }
}

// ---------------- launch ----------------
extern "C" void kernel_launch(void* const* d_in, const int* in_sizes, int n_in,
                              void* d_out, int out_size, void* d_ws, size_t ws_size,
                              hipStream_t stream) {
    (void)in_sizes; (void)n_in; (void)out_size;
    const float* x    = (const float*)d_in[0];
    const int*   ei   = (const int*)  d_in[1];
    const int*   batch= (const int*)  d_in[2];
    const float* tW   = (const float*)d_in[3];
    const float* tb   = (const float*)d_in[4];
    const float* W0   = (const float*)d_in[5];
    const float* as0  = (const float*)d_in[6];
    const float* ad0  = (const float*)d_in[7];
    const float* b0   = (const float*)d_in[8];
    const float* g0   = (const float*)d_in[9];
    const float* be0  = (const float*)d_in[10];
    const float* W1   = (const float*)d_in[11];
    const float* as1  = (const float*)d_in[12];
    const float* ad1  = (const float*)d_in[13];
    const float* b1   = (const float*)d_in[14];
    const float* g1   = (const float*)d_in[15];
    const float* be1  = (const float*)d_in[16];
    const float* W2   = (const float*)d_in[17];
    const float* as2  = (const float*)d_in[18];
    const float* ad2  = (const float*)d_in[19];
    const float* b2   = (const float*)d_in[20];
    const float* g2   = (const float*)d_in[21];
    const float* be2  = (const float*)d_in[22];
    const float* mW1  = (const float*)d_in[23];
    const float* mb1  = (const float*)d_in[24];
    const float* mW2  = (const float*)d_in[25];
    const float* mb2  = (const float*)d_in[26];
    float* outp = (float*)d_out;

    size_t off = 0;
    auto carve = [&](size_t bytes) -> void* {
        void* p = (char*)d_ws + off;
        off = (off + bytes + 255) & ~(size_t)255;
        return p;
    };
    f16* big1 = (f16*)carve((size_t)NN*W3P*2);          // h / y buffers
    f16* big2 = (f16*)carve((size_t)NN*W3P*2);          // hp buffer
    f16* Wt   = (f16*)carve((size_t)W3*W3P*2);          // transposed (scaled) weights
    float* a_s   = (float*)carve((size_t)NN*3*4);
    float* a_d   = (float*)carve((size_t)NN*3*4);
    float* psum  = (float*)carve((size_t)64*W3*4);      // bnstat partials
    float* psq   = (float*)carve((size_t)64*W3*4);
    float* sc    = (float*)carve((size_t)W3*4);
    float* sh    = (float*)carve((size_t)W3*4);
    float* dvec  = (float*)carve((size_t)W3*4);
    float* pooled= (float*)carve((size_t)NGR*EMB*4);
    int*   grp   = (int*)carve((size_t)(NGR+1)*4);
    int*   deg   = (int*)carve((size_t)NN*4);           // reused as cursor
    int*   rp    = (int*)carve((size_t)(NN+1)*4);
    int*   csrc  = (int*)carve((size_t)ELP*4);

    if (ws_size < off) return;

    // CSR build
    k_zero_i32<<<cdiv_i(NN,256),256,0,stream>>>(deg, NN);
    k_deg<<<cdiv_i(ELP,256),256,0,stream>>>(ei, deg);
    k_scan<<<1,1024,0,stream>>>(deg, rp);
    k_copy_i32<<<cdiv_i(NN,256),256,0,stream>>>(rp, deg, NN);
    k_fill<<<cdiv_i(ELP,256),256,0,stream>>>(ei, deg, csrc);
    k_grp<<<1,256,0,stream>>>(batch, grp);

    // h0
    k_build_h<<<cdiv_i((long long)NN*EMBP,256),256,0,stream>>>(x, tW, tb, big1);

    struct Layer { const float* W; const float* as; const float* ad; const float* b;
                   const float* g; const float* be; int H; int K; int KP; };
    Layer layers[3] = {
        {W0, as0, ad0, b0, g0, be0, 3, EMB, EMBP},
        {W1, as1, ad1, b1, g1, be1, 3, W3,  W3P },
        {W2, as2, ad2, b2, g2, be2, 1, W3,  W3P },
    };

    for (int L = 0; L < 3; L++){
        Layer& ly = layers[L];
        int Wout  = ly.H * EMB;                 // 2340 / 2340 / 780
        int SPout = (Wout == W3) ? W3P : EMBP;  // 2368 / 2368 / 832
        const float* scale = (L == 0) ? nullptr : sc;

        // Wt <- W^T (scaled by prev BN scale); dvec <- sh @ W (L>0)
        dim3 tg(cdiv_i(Wout,32), cdiv_i(ly.KP,32));
        k_transpose<<<tg, dim3(32,8), 0, stream>>>(ly.W, Wt, scale, ly.K, Wout, ly.KP);
        k_zero_f32<<<cdiv_i(W3,256),256,0,stream>>>(dvec, W3);
        if (L > 0){
            dim3 dg(cdiv_i(Wout,256), DVEC_KSPLIT);
            k_dvec<<<dg,256,0,stream>>>(ly.W, sh, dvec, ly.K, Wout);
        }

        // hp = BN(h) @ W via f16 MFMA (BN folded), XCD-pinned strips, BK=64
        int Mtiles = cdiv_i(NN,128), NT = cdiv_i(Wout,128);
        int nb = ((Mtiles+7)/8)*8*NT;
        k_gemm_mfma<<<nb, 256, 0, stream>>>(big1, Wt, dvec, big2, NN, Wout, ly.KP, SPout, Mtiles, NT);

        // attention coefficients
        k_att<<<NN, ly.H*64, 0, stream>>>(big2, ly.as, ly.ad, a_s, a_d, ly.H, SPout);

        // softmax + aggregate + bias + tanh -> big1 (pre-BN y, pads zeroed)
        if (ly.H == 3)
            k_agg2<3><<<NN,256,0,stream>>>(big2, rp, csrc, a_s, a_d, ly.b, big1, SPout, Wout);
        else
            k_agg2<1><<<NN,256,0,stream>>>(big2, rp, csrc, a_s, a_d, ly.b, big1, SPout, Wout);

        // BN stats (partials, no atomics) + fold coefficients
        dim3 gs(cdiv_i(Wout/4,256), 64);
        k_bnstat<<<gs,256,0,stream>>>(big1, psum, psq, Wout, SPout);
        k_bnfin<<<cdiv_i(Wout,256),256,0,stream>>>(psum, psq, ly.g, ly.be, sc, sh, Wout);
    }

    // segmented pooling (raw y) + MLP (applies final BN affine on pooled means)
    k_pool<<<NGR,256,0,stream>>>(big1, grp, pooled);
    k_mlp<<<NGR,256,0,stream>>>(pooled, grp, sc, sh, mW1, mb1, mW2, mb2, outp);
}

// Round 8
// 1651.012 us; speedup vs baseline: 1.0165x; 1.0165x over previous
//
#include <hip/hip_runtime.h>
#include <math.h>

#define NN   20000
#define EE   80000
#define ELP  100000   // EE + NN self loops
#define NGR  64
#define EMB  780
#define W3   2340
#define EMBP 832      // 780 padded to mult of 64 (BK)
#define W3P  2368     // 2340 padded to mult of 64
#define NZ   (W3+8)   // dvec length (incl. attention-correction slots)

static inline int cdiv_i(long long a, long long b){ return (int)((a + b - 1) / b); }

typedef _Float16 f16;
typedef _Float16 f16x4 __attribute__((ext_vector_type(4)));
typedef _Float16 f16x8 __attribute__((ext_vector_type(8)));
typedef float    f32x4 __attribute__((ext_vector_type(4)));

__device__ __forceinline__ void async_ld16(const f16* g, f16* l){
    __builtin_amdgcn_global_load_lds(
        (const __attribute__((address_space(1))) unsigned int*)g,
        (__attribute__((address_space(3))) unsigned int*)l,
        16, 0, 0);
}

// ---------------- utility kernels ----------------
__global__ void k_zero_f32(float* p, int n){
    int i = blockIdx.x*256 + threadIdx.x; if (i < n) p[i] = 0.f;
}
__global__ void k_zero_i32(int* p, int n){
    int i = blockIdx.x*256 + threadIdx.x; if (i < n) p[i] = 0;
}
__global__ void k_copy_i32(const int* __restrict__ s, int* __restrict__ d, int n){
    int i = blockIdx.x*256 + threadIdx.x; if (i < n) d[i] = s[i];
}

// W [K,N] fp32 -> Wt [N,KP] f16, optional per-k scale (BN fold), pad k zeroed
__global__ void k_transpose(const float* __restrict__ W, f16* __restrict__ Wt,
                            const float* __restrict__ sc, int K, int N, int KP){
    __shared__ float T[32][33];
    int n0 = blockIdx.x*32, k0 = blockIdx.y*32;
    int tx = threadIdx.x, ty = threadIdx.y;   // 32 x 8
#pragma unroll
    for (int r = 0; r < 4; r++){
        int k = k0 + ty + r*8;
        float v = 0.f;
        if (k < K && n0 + tx < N){
            v = W[(size_t)k*N + n0 + tx];
            if (sc) v *= sc[k];
        }
        T[ty + r*8][tx] = v;
    }
    __syncthreads();
#pragma unroll
    for (int r = 0; r < 4; r++){
        int n = n0 + ty + r*8;
        int k = k0 + tx;
        if (n < N && k < KP) Wt[(size_t)n*KP + k] = (f16)T[tx][ty + r*8];
    }
}

// Attention fold: Wt[N+i][k] = sc[k] * sum_c W[k, h*EMB+c] * att[i][c]
// i in [0,H): att_src head i ; i in [H,2H): att_dst head i-H. One wave per k.
__global__ void k_wvec(const float* __restrict__ W, const float* __restrict__ asrc,
                       const float* __restrict__ adst, const float* __restrict__ sc,
                       f16* __restrict__ Wt, int K, int N, int KP, int H){
    int k = blockIdx.x*4 + (threadIdx.x >> 6);
    int lane = threadIdx.x & 63;
    if (k >= K) return;
    const float* row = W + (size_t)k*N;
    float acc[6];
#pragma unroll
    for (int i = 0; i < 6; i++) acc[i] = 0.f;
    for (int c = lane; c < EMB; c += 64){
        for (int h = 0; h < H; h++){
            float wv = row[h*EMB + c];
            acc[h]     += wv * asrc[h*EMB + c];
            acc[H + h] += wv * adst[h*EMB + c];
        }
    }
    float s = sc ? sc[k] : 1.f;
    for (int i = 0; i < 2*H; i++){
        float v = acc[i];
#pragma unroll
        for (int off = 32; off; off >>= 1) v += __shfl_xor(v, off);
        if (lane == 0) Wt[(size_t)(N + i)*KP + k] = (f16)(v * s);
    }
}

// dvec[N+i] = sum_c dvec[h*EMB+c] * att[i][c]  (rank-1 correction for a_s/a_d)
__global__ void k_wfin(const float* __restrict__ asrc, const float* __restrict__ adst,
                       float* __restrict__ dvec, int N, int H){
    int wv = threadIdx.x >> 6, lane = threadIdx.x & 63;
    for (int i = wv; i < 2*H; i += 4){
        int h = (i < H) ? i : (i - H);
        const float* att = (i < H) ? (asrc + h*EMB) : (adst + h*EMB);
        float s = 0.f;
        for (int c = lane; c < EMB; c += 64) s += dvec[h*EMB + c] * att[c];
#pragma unroll
        for (int off = 32; off; off >>= 1) s += __shfl_xor(s, off);
        if (lane == 0) dvec[N + i] = s;
    }
}

// dvec[n] += sum_{k in slice} sh[k] * W[k,n]  — coalesced, K split across blockIdx.y
#define DVEC_KSPLIT 32
__global__ void k_dvec(const float* __restrict__ W, const float* __restrict__ sh,
                       float* __restrict__ dvec, int K, int N){
    int n = blockIdx.x*256 + threadIdx.x;
    if (n >= N) return;
    int slice = blockIdx.y;
    int k0 = (int)(((long long)K * slice) / DVEC_KSPLIT);
    int k1 = (int)(((long long)K * (slice+1)) / DVEC_KSPLIT);
    float s = 0.f;
    for (int k = k0; k < k1; k++) s += sh[k] * W[(size_t)k*N + n];
    atomicAdd(&dvec[n], s);
}

// ---------------- h0 ----------------
__global__ void k_build_h(const float* __restrict__ x, const float* __restrict__ tW,
                          const float* __restrict__ tb, f16* __restrict__ h){
    int idx = blockIdx.x*256 + threadIdx.x;
    if (idx >= NN*EMBP) return;
    int n = idx / EMBP, c = idx - n*EMBP;
    const float* xr = x + (size_t)n*772;
    float v;
    if (c < 768) v = xr[c];
    else if (c < EMB){
        int j = c - 768;
        v = tb[j] + xr[768]*tW[j] + xr[769]*tW[12+j] + xr[770]*tW[24+j] + xr[771]*tW[36+j];
    } else v = 0.f;
    h[idx] = (f16)v;
}

// ---------------- CSR build ----------------
__global__ void k_deg(const int* __restrict__ ei, int* __restrict__ deg){
    int k = blockIdx.x*256 + threadIdx.x; if (k >= ELP) return;
    int d = (k < EE) ? ei[EE + k] : (k - EE);
    atomicAdd(&deg[d], 1);
}

__global__ __launch_bounds__(1024) void k_scan(const int* __restrict__ deg, int* __restrict__ rp){
    __shared__ int part[1024];
    int tid = threadIdx.x;
    int i0 = tid*20;
    int n = (i0 < NN) ? min(20, NN - i0) : 0;
    int s = 0;
    for (int k = 0; k < n; k++) s += deg[i0+k];
    part[tid] = s; __syncthreads();
    for (int off = 1; off < 1024; off <<= 1){
        int t = (tid >= off) ? part[tid-off] : 0;
        __syncthreads();
        part[tid] += t;
        __syncthreads();
    }
    int run = part[tid] - s;   // exclusive prefix
    for (int k = 0; k < n; k++){ rp[i0+k] = run; run += deg[i0+k]; }
    if (tid == 1023) rp[NN] = part[1023];
}

__global__ void k_fill(const int* __restrict__ ei, int* __restrict__ cursor, int* __restrict__ csrc){
    int k = blockIdx.x*256 + threadIdx.x; if (k >= ELP) return;
    int s, d;
    if (k < EE){ s = ei[k]; d = ei[EE + k]; } else { s = k - EE; d = s; }
    int pos = atomicAdd(&cursor[d], 1);
    csrc[pos] = s;
}

__global__ void k_grp(const int* __restrict__ batch, int* __restrict__ grp){
    int g = blockIdx.x*256 + threadIdx.x; if (g > NGR) return;
    int lo = 0, hi = NN;
    while (lo < hi){ int mid = (lo+hi)>>1; if (batch[mid] < g) lo = mid+1; else hi = mid; }
    grp[g] = lo;
}

// ------ MFMA f16 GEMM, XCD-pinned strips, BK=64; cols [N,NB) -> a_sd fp32 ------
__global__ __launch_bounds__(256) void k_gemm_mfma(const f16* __restrict__ A,
                                                   const f16* __restrict__ Bt,
                                                   const float* __restrict__ dvec,
                                                   f16* __restrict__ C,
                                                   float* __restrict__ a_sd,
                                                   int M, int N, int NB, int H,
                                                   int KP, int SN,
                                                   int Mtiles, int NT){
    int bid = blockIdx.x;
    int xcd = bid & 7;
    int j   = bid >> 3;
    int sl  = j / NT;
    int nt  = j - sl*NT;
    int mt  = sl*8 + xcd;
    if (mt >= Mtiles) return;
    int m0 = mt*128, n0 = nt*128;

    __shared__ f16 As[128*64];   // two 128x32 panels
    __shared__ f16 Bs[128*64];
    int tid = threadIdx.x;
    int w = tid >> 6, lane = tid & 63;

    int lrow = lane >> 2;
    int lko  = (lane & 3) * 8;

    int i2a = w*2, i2b = w*2 + 1;
    const f16* gA0 = A  + (size_t)min(m0 + i2a*16 + lrow, M-1)*KP + lko;
    const f16* gA1 = A  + (size_t)min(m0 + i2b*16 + lrow, M-1)*KP + lko;
    const f16* gB0 = Bt + (size_t)min(n0 + i2a*16 + lrow, NB-1)*KP + lko;
    const f16* gB1 = Bt + (size_t)min(n0 + i2b*16 + lrow, NB-1)*KP + lko;
    f16* lA0 = &As[i2a*512]; f16* lA1 = &As[i2b*512];
    f16* lB0 = &Bs[i2a*512]; f16* lB1 = &Bs[i2b*512];

    f32x4 acc[4][4];
#pragma unroll
    for (int i = 0; i < 4; i++)
#pragma unroll
        for (int j2 = 0; j2 < 4; j2++) acc[i][j2] = (f32x4)0.f;

    int wm = (w & 1) * 64, wn = (w >> 1) * 64;
    int lq = lane >> 4, lm = lane & 15;

    for (int kk = 0; kk < KP; kk += 64){
        __syncthreads();
        async_ld16(gA0 + kk, lA0);
        async_ld16(gA1 + kk, lA1);
        async_ld16(gB0 + kk, lB0);
        async_ld16(gB1 + kk, lB1);
        async_ld16(gA0 + kk + 32, lA0 + 4096);
        async_ld16(gA1 + kk + 32, lA1 + 4096);
        async_ld16(gB0 + kk + 32, lB0 + 4096);
        async_ld16(gB1 + kk + 32, lB1 + 4096);
        __syncthreads();

#pragma unroll
        for (int half = 0; half < 2; half++){
            const f16* Ap = As + half*4096;
            const f16* Bp = Bs + half*4096;
            f16x8 aF[4], bF[4];
#pragma unroll
            for (int mi = 0; mi < 4; mi++)
                aF[mi] = *(const f16x8*)&Ap[(wm + mi*16 + lm)*32 + lq*8];
#pragma unroll
            for (int ni = 0; ni < 4; ni++)
                bF[ni] = *(const f16x8*)&Bp[(wn + ni*16 + lm)*32 + lq*8];
#pragma unroll
            for (int mi = 0; mi < 4; mi++)
#pragma unroll
                for (int ni = 0; ni < 4; ni++)
                    acc[mi][ni] = __builtin_amdgcn_mfma_f32_16x16x32_f16(aF[mi], bF[ni], acc[mi][ni], 0, 0, 0);
        }
    }

#pragma unroll
    for (int mi = 0; mi < 4; mi++){
#pragma unroll
        for (int ni = 0; ni < 4; ni++){
            int col = n0 + wn + ni*16 + lm;
            int rbase = m0 + wm + mi*16 + lq*4;
            if (col < N){
                float dv = dvec[col];
#pragma unroll
                for (int r = 0; r < 4; r++){
                    int row = rbase + r;
                    if (row < M)
                        C[(size_t)row*SN + col] = (f16)(acc[mi][ni][r] + dv);
                }
            } else if (col < NB){
                int jc = col - N;
                int idx = (jc < H) ? jc : (3 + jc - H);   // a_s[0..H) | a_d at +3
                float dv = dvec[col];
#pragma unroll
                for (int r = 0; r < 4; r++){
                    int row = rbase + r;
                    if (row < M)
                        a_sd[(size_t)row*6 + idx] = acc[mi][ni][r] + dv;
                }
            }
        }
    }
}

// ---- per-dst softmax + aggregation + bias + tanh: barrier-free, LDS-free, f16x8 ----
template<int H>
__global__ __launch_bounds__(256) void k_agg2(const f16* __restrict__ hp, const int* __restrict__ rp,
                                              const int* __restrict__ csrc, const float* __restrict__ a_sd,
                                              const float* __restrict__ bias,
                                              f16* __restrict__ y, int SP, int W){
    int n = blockIdx.x, tid = threadIdx.x, lane = tid & 63;
    int beg = rp[n], deg = rp[n+1] - beg;

    float adv[H];
#pragma unroll
    for (int h = 0; h < H; h++) adv[h] = a_sd[(size_t)n*6 + 3 + h];

    // pass 1: max
    float mx[H];
#pragma unroll
    for (int h = 0; h < H; h++) mx[h] = -1e30f;
    for (int base = 0; base < deg; base += 64){
        int e = base + lane;
        if (e < deg){
            int s = csrc[beg + e];
#pragma unroll
            for (int h = 0; h < H; h++){
                float t = a_sd[(size_t)s*6 + h] + adv[h];
                t = t > 0.f ? t : 0.2f*t;
                mx[h] = fmaxf(mx[h], t);
            }
        }
    }
#pragma unroll
    for (int off = 32; off; off >>= 1)
#pragma unroll
        for (int h = 0; h < H; h++) mx[h] = fmaxf(mx[h], __shfl_xor(mx[h], off));

    // pass 2: denom
    float dn[H];
#pragma unroll
    for (int h = 0; h < H; h++) dn[h] = 0.f;
    for (int base = 0; base < deg; base += 64){
        int e = base + lane;
        if (e < deg){
            int s = csrc[beg + e];
#pragma unroll
            for (int h = 0; h < H; h++){
                float t = a_sd[(size_t)s*6 + h] + adv[h];
                t = t > 0.f ? t : 0.2f*t;
                dn[h] += expf(t - mx[h]);
            }
        }
    }
#pragma unroll
    for (int off = 32; off; off >>= 1)
#pragma unroll
        for (int h = 0; h < H; h++) dn[h] += __shfl_xor(dn[h], off);
    float inv[H];
#pragma unroll
    for (int h = 0; h < H; h++) inv[h] = 1.f / (dn[h] + 1e-16f);

    // column groups: c = 2048*g + tid*8
    float acc[2][8];
#pragma unroll
    for (int g = 0; g < 2; g++)
#pragma unroll
        for (int j = 0; j < 8; j++) acc[g][j] = 0.f;
    int  cg[2];  cg[0] = tid*8; cg[1] = 2048 + tid*8;
    bool act[2]; act[0] = cg[0] < W; act[1] = cg[1] < W;
    int hlo[2], hhi[2], nsp[2];
#pragma unroll
    for (int g = 0; g < 2; g++){
        int c = cg[g];
        int hl = min(c / EMB, H-1);
        int hh = min((c+7) / EMB, H-1);
        hlo[g] = hl; hhi[g] = hh;
        nsp[g] = (hh > hl) ? (EMB*(hl+1) - c) : 8;
    }

    for (int base = 0; base < deg; base += 64){
        int cnt = min(64, deg - base);
        int sl = 0; float al[H];
        {
            int e = base + lane;
            if (e < deg){
                sl = csrc[beg + e];
#pragma unroll
                for (int h = 0; h < H; h++){
                    float t = a_sd[(size_t)sl*6 + h] + adv[h];
                    t = t > 0.f ? t : 0.2f*t;
                    al[h] = expf(t - mx[h]) * inv[h];
                }
            } else {
#pragma unroll
                for (int h = 0; h < H; h++) al[h] = 0.f;
            }
        }
#pragma unroll 2
        for (int e = 0; e < cnt; e++){
            int s = __shfl(sl, e);
            float a0 = __shfl(al[0], e);
            float a1 = (H==3) ? __shfl(al[1], e) : a0;
            float a2 = (H==3) ? __shfl(al[2], e) : a0;
            const f16* row = hp + (size_t)s*SP;
#pragma unroll
            for (int g = 0; g < 2; g++){
                if (act[g]){
                    f16x8 v = *(const f16x8*)(row + cg[g]);
                    float lo = (hlo[g]==0) ? a0 : (hlo[g]==1 ? a1 : a2);
                    float hi = (hhi[g]==0) ? a0 : (hhi[g]==1 ? a1 : a2);
#pragma unroll
                    for (int j = 0; j < 8; j++){
                        float alj = (j < nsp[g]) ? lo : hi;
                        acc[g][j] += alj * (float)v[j];
                    }
                }
            }
        }
    }

    // epilogue: bias + tanh + write (pad cols -> 0)
#pragma unroll
    for (int g = 0; g < 2; g++){
        int c = cg[g];
        if (c < SP){
            f16x8 o;
#pragma unroll
            for (int j = 0; j < 8; j++){
                float vv = (c + j < W) ? tanhf(acc[g][j] + bias[c+j]) : 0.f;
                o[j] = (f16)vv;
            }
            *(f16x8*)(y + (size_t)n*SP + c) = o;
        }
    }
}

// ---------------- BatchNorm stats: 128-slice partials (no atomics) ----------------
__global__ void k_bnstat(const f16* __restrict__ y, float* __restrict__ ps,
                         float* __restrict__ pq, int W, int SP){
    int c0 = (blockIdx.x*256 + threadIdx.x)*4;
    if (c0 >= W) return;
    int slice = blockIdx.y;   // 0..127
    float s[4] = {0,0,0,0}, q[4] = {0,0,0,0};
    for (int r = slice; r < NN; r += 128){
        f16x4 u = *(const f16x4*)(y + (size_t)r*SP + c0);
#pragma unroll
        for (int j = 0; j < 4; j++){ float v = (float)u[j]; s[j] += v; q[j] += v*v; }
    }
#pragma unroll
    for (int j = 0; j < 4; j++){
        ps[(size_t)slice*W3 + c0+j] = s[j];
        pq[(size_t)slice*W3 + c0+j] = q[j];
    }
}

// reduce partials; sc = istd*gamma, sh = beta - mu*istd*gamma; also zero dvec for next layer
__global__ void k_bnfin(const float* __restrict__ ps, const float* __restrict__ pq,
                        const float* __restrict__ gamma, const float* __restrict__ beta,
                        float* __restrict__ sc, float* __restrict__ sh,
                        float* __restrict__ dvec, int W, int zn){
    int c = blockIdx.x*256 + threadIdx.x;
    if (c < W){
        float m = 0.f, q = 0.f;
        for (int s = 0; s < 128; s++){ m += ps[(size_t)s*W3 + c]; q += pq[(size_t)s*W3 + c]; }
        m *= (1.f/NN);
        float v = q * (1.f/NN) - m*m;
        float is = 1.f / sqrtf(v + 1e-5f);
        float g = gamma[c];
        sc[c] = is * g;
        sh[c] = beta[c] - m * is * g;
    }
    if (c < zn) dvec[c] = 0.f;
}

// ---------------- segmented pooling (raw y; BN folded into MLP) ----------------
__global__ void k_pool(const f16* __restrict__ h, const int* __restrict__ grp,
                       float* __restrict__ pooled){
    int g = blockIdx.x;
    int c = threadIdx.x*4;
    if (c >= EMB) return;
    int r0 = grp[g], r1 = grp[g+1];
    float s0=0.f, s1=0.f, s2=0.f, s3=0.f;
    for (int r = r0; r < r1; r++){
        f16x4 u = *(const f16x4*)(h + (size_t)r*EMBP + c);
        s0 += (float)u[0]; s1 += (float)u[1]; s2 += (float)u[2]; s3 += (float)u[3];
    }
    pooled[g*EMB + c] = s0; pooled[g*EMB + c+1] = s1;
    pooled[g*EMB + c+2] = s2; pooled[g*EMB + c+3] = s3;
}

__global__ __launch_bounds__(256) void k_mlp(const float* __restrict__ pooled, const int* __restrict__ grp,
                                             const float* __restrict__ sc, const float* __restrict__ sh,
                                             const float* __restrict__ W1, const float* __restrict__ b1,
                                             const float* __restrict__ W2, const float* __restrict__ b2,
                                             float* __restrict__ out){
    __shared__ float p[EMB];
    __shared__ float hid[128];
    int g = blockIdx.x, tid = threadIdx.x;
    int cnt = grp[g+1] - grp[g];
    float ic = 1.f / fmaxf((float)cnt, 1.f);
    for (int c = tid; c < EMB; c += 256){
        float v = pooled[g*EMB + c] * ic * sc[c] + sh[c];   // BN(mean) — affine commutes with mean
        p[c] = v > 0.f ? v : 0.f;
    }
    __syncthreads();
    if (tid < 128){
        float s = b1[tid];
        for (int k = 0; k < EMB; k++) s += p[k] * W1[k*128 + tid];
        hid[tid] = tanhf(s);
    }
    __syncthreads();
    if (tid < 64){
        float s = b2[tid];
        for (int k = 0; k < 128; k++) s += hid[k] * W2[k*64 + tid];
        out[g*64 + tid] = s;
    }
}

// ---------------- launch ----------------
extern "C" void kernel_launch(void* const* d_in, const int* in_sizes, int n_in,
                              void* d_out, int out_size, void* d_ws, size_t ws_size,
                              hipStream_t stream) {
    (void)in_sizes; (void)n_in; (void)out_size;
    const float* x    = (const float*)d_in[0];
    const int*   ei   = (const int*)  d_in[1];
    const int*   batch= (const int*)  d_in[2];
    const float* tW   = (const float*)d_in[3];
    const float* tb   = (const float*)d_in[4];
    const float* W0   = (const float*)d_in[5];
    const float* as0  = (const float*)d_in[6];
    const float* ad0  = (const float*)d_in[7];
    const float* b0   = (const float*)d_in[8];
    const float* g0   = (const float*)d_in[9];
    const float* be0  = (const float*)d_in[10];
    const float* W1   = (const float*)d_in[11];
    const float* as1  = (const float*)d_in[12];
    const float* ad1  = (const float*)d_in[13];
    const float* b1   = (const float*)d_in[14];
    const float* g1   = (const float*)d_in[15];
    const float* be1  = (const float*)d_in[16];
    const float* W2   = (const float*)d_in[17];
    const float* as2  = (const float*)d_in[18];
    const float* ad2  = (const float*)d_in[19];
    const float* b2   = (const float*)d_in[20];
    const float* g2   = (const float*)d_in[21];
    const float* be2  = (const float*)d_in[22];
    const float* mW1  = (const float*)d_in[23];
    const float* mb1  = (const float*)d_in[24];
    const float* mW2  = (const float*)d_in[25];
    const float* mb2  = (const float*)d_in[26];
    float* outp = (float*)d_out;

    size_t off = 0;
    auto carve = [&](size_t bytes) -> void* {
        void* p = (char*)d_ws + off;
        off = (off + bytes + 255) & ~(size_t)255;
        return p;
    };
    f16* big1 = (f16*)carve((size_t)NN*W3P*2);          // h / y buffers
    f16* big2 = (f16*)carve((size_t)NN*W3P*2);          // hp buffer
    f16* Wt   = (f16*)carve((size_t)NZ*W3P*2);          // transposed weights + attention rows
    float* a_sd  = (float*)carve((size_t)NN*6*4);       // [n][a_s(3), a_d(3)]
    float* psum  = (float*)carve((size_t)128*W3*4);     // bnstat partials
    float* psq   = (float*)carve((size_t)128*W3*4);
    float* sc    = (float*)carve((size_t)W3*4);
    float* sh    = (float*)carve((size_t)W3*4);
    float* dvec  = (float*)carve((size_t)NZ*4);
    float* pooled= (float*)carve((size_t)NGR*EMB*4);
    int*   grp   = (int*)carve((size_t)(NGR+1)*4);
    int*   deg   = (int*)carve((size_t)NN*4);           // reused as cursor
    int*   rp    = (int*)carve((size_t)(NN+1)*4);
    int*   csrc  = (int*)carve((size_t)ELP*4);

    if (ws_size < off) return;

    // CSR build
    k_zero_i32<<<cdiv_i(NN,256),256,0,stream>>>(deg, NN);
    k_deg<<<cdiv_i(ELP,256),256,0,stream>>>(ei, deg);
    k_scan<<<1,1024,0,stream>>>(deg, rp);
    k_copy_i32<<<cdiv_i(NN,256),256,0,stream>>>(rp, deg, NN);
    k_fill<<<cdiv_i(ELP,256),256,0,stream>>>(ei, deg, csrc);
    k_grp<<<1,256,0,stream>>>(batch, grp);

    // h0 + initial dvec zero (layer 0 has no BN fold)
    k_build_h<<<cdiv_i((long long)NN*EMBP,256),256,0,stream>>>(x, tW, tb, big1);
    k_zero_f32<<<cdiv_i(NZ,256),256,0,stream>>>(dvec, NZ);

    struct Layer { const float* W; const float* as; const float* ad; const float* b;
                   const float* g; const float* be; int H; int K; int KP; };
    Layer layers[3] = {
        {W0, as0, ad0, b0, g0, be0, 3, EMB, EMBP},
        {W1, as1, ad1, b1, g1, be1, 3, W3,  W3P },
        {W2, as2, ad2, b2, g2, be2, 1, W3,  W3P },
    };

    for (int L = 0; L < 3; L++){
        Layer& ly = layers[L];
        int Wout  = ly.H * EMB;                 // 2340 / 2340 / 780
        int NB    = Wout + 2*ly.H;              // + attention columns
        int SPout = (Wout == W3) ? W3P : EMBP;  // 2368 / 2368 / 832
        const float* scale = (L == 0) ? nullptr : sc;

        // Wt rows [0,Wout): scaled W^T ; rows [Wout, NB): attention fold vectors
        dim3 tg(cdiv_i(Wout,32), cdiv_i(ly.KP,32));
        k_transpose<<<tg, dim3(32,8), 0, stream>>>(ly.W, Wt, scale, ly.K, Wout, ly.KP);
        k_wvec<<<cdiv_i(ly.K,4),256,0,stream>>>(ly.W, ly.as, ly.ad, scale, Wt, ly.K, Wout, ly.KP, ly.H);
        if (L > 0){
            dim3 dg(cdiv_i(Wout,256), DVEC_KSPLIT);
            k_dvec<<<dg,256,0,stream>>>(ly.W, sh, dvec, ly.K, Wout);
        }
        k_wfin<<<1,256,0,stream>>>(ly.as, ly.ad, dvec, Wout, ly.H);

        // hp (+ a_s/a_d) = BN(h) @ [W | w_att] via f16 MFMA, XCD-pinned strips, BK=64
        int Mtiles = cdiv_i(NN,128), NT = cdiv_i(NB,128);
        int nb = ((Mtiles+7)/8)*8*NT;
        k_gemm_mfma<<<nb, 256, 0, stream>>>(big1, Wt, dvec, big2, a_sd,
                                            NN, Wout, NB, ly.H, ly.KP, SPout, Mtiles, NT);

        // softmax + aggregate + bias + tanh -> big1 (pre-BN y, pads zeroed)
        if (ly.H == 3)
            k_agg2<3><<<NN,256,0,stream>>>(big2, rp, csrc, a_sd, ly.b, big1, SPout, Wout);
        else
            k_agg2<1><<<NN,256,0,stream>>>(big2, rp, csrc, a_sd, ly.b, big1, SPout, Wout);

        // BN stats + fold coefficients (+ zero dvec for next layer)
        dim3 gs(cdiv_i(Wout/4,256), 128);
        k_bnstat<<<gs,256,0,stream>>>(big1, psum, psq, Wout, SPout);
        int zn = (L < 2) ? NZ : 0;
        k_bnfin<<<cdiv_i(Wout,256),256,0,stream>>>(psum, psq, ly.g, ly.be, sc, sh, dvec, Wout, zn);
    }

    // segmented pooling (raw y) + MLP (applies final BN affine on pooled means)
    k_pool<<<NGR,256,0,stream>>>(big1, grp, pooled);
    k_mlp<<<NGR,256,0,stream>>>(pooled, grp, sc, sh, mW1, mb1, mW2, mb2, outp);
}

// Round 9
// 1489.501 us; speedup vs baseline: 1.1267x; 1.1084x over previous
//
#include <hip/hip_runtime.h>
#include <math.h>

#define NN   20000
#define EE   80000
#define ELP  100000   // EE + NN self loops
#define NGR  64
#define EMB  780
#define W3   2340
#define EMBP 832      // 780 padded to mult of 64 (BK)
#define W3P  2368     // 2340 padded to mult of 64
#define NZ   (W3+8)   // dvec length (incl. attention-correction slots)

static inline int cdiv_i(long long a, long long b){ return (int)((a + b - 1) / b); }

typedef _Float16 f16;
typedef _Float16 f16x4 __attribute__((ext_vector_type(4)));
typedef _Float16 f16x8 __attribute__((ext_vector_type(8)));
typedef float    f32x4 __attribute__((ext_vector_type(4)));

__device__ __forceinline__ void async_ld16(const f16* g, f16* l){
    __builtin_amdgcn_global_load_lds(
        (const __attribute__((address_space(1))) unsigned int*)g,
        (__attribute__((address_space(3))) unsigned int*)l,
        16, 0, 0);
}

// ---------------- utility kernels ----------------
__global__ void k_zero_f32(float* p, int n){
    int i = blockIdx.x*256 + threadIdx.x; if (i < n) p[i] = 0.f;
}
__global__ void k_zero_i32(int* p, int n){
    int i = blockIdx.x*256 + threadIdx.x; if (i < n) p[i] = 0;
}

// W [K,N] fp32 -> Wt [N,KP] f16 (scaled by sc for BN fold); also accumulates
// dvec[n] += sum_k sh[k]*W[k,n] (RAW W) via per-tile reduction + 32 atomics.
__global__ void k_transpose(const float* __restrict__ W, f16* __restrict__ Wt,
                            const float* __restrict__ sc, const float* __restrict__ sh,
                            float* __restrict__ dvec, int K, int N, int KP){
    __shared__ float T[32][33];
    __shared__ float D[8][33];
    int n0 = blockIdx.x*32, k0 = blockIdx.y*32;
    int tx = threadIdx.x, ty = threadIdx.y;   // 32 x 8
    float raw[4];
#pragma unroll
    for (int r = 0; r < 4; r++){
        int k = k0 + ty + r*8;
        float w = 0.f;
        if (k < K && n0 + tx < N) w = W[(size_t)k*N + n0 + tx];
        raw[r] = w;
        T[ty + r*8][tx] = sc ? w * ((k < K) ? sc[k] : 0.f) : w;
    }
    if (sh){
        float p = 0.f;
#pragma unroll
        for (int r = 0; r < 4; r++){
            int k = k0 + ty + r*8;
            if (k < K) p += sh[k] * raw[r];
        }
        D[ty][tx] = p;
    }
    __syncthreads();
#pragma unroll
    for (int r = 0; r < 4; r++){
        int n = n0 + ty + r*8;
        int k = k0 + tx;
        if (n < N && k < KP) Wt[(size_t)n*KP + k] = (f16)T[tx][ty + r*8];
    }
    if (sh && ty == 0 && n0 + tx < N){
        float s = 0.f;
#pragma unroll
        for (int j = 0; j < 8; j++) s += D[j][tx];
        atomicAdd(&dvec[n0 + tx], s);
    }
}

// Attention fold: Wt[N+i][k] = sc[k] * sum_c W[k, h*EMB+c] * att[i][c]
// block 0 additionally computes dvec[N+i] (rank-1 correction), dvec core already final.
__global__ void k_wvec(const float* __restrict__ W, const float* __restrict__ asrc,
                       const float* __restrict__ adst, const float* __restrict__ sc,
                       f16* __restrict__ Wt, float* __restrict__ dvec,
                       int K, int N, int KP, int H){
    int k = blockIdx.x*4 + (threadIdx.x >> 6);
    int lane = threadIdx.x & 63;
    if (k < K){
        const float* row = W + (size_t)k*N;
        float acc[6];
#pragma unroll
        for (int i = 0; i < 6; i++) acc[i] = 0.f;
        for (int c = lane; c < EMB; c += 64){
            for (int h = 0; h < H; h++){
                float wv = row[h*EMB + c];
                acc[h]     += wv * asrc[h*EMB + c];
                acc[H + h] += wv * adst[h*EMB + c];
            }
        }
        float s = sc ? sc[k] : 1.f;
        for (int i = 0; i < 2*H; i++){
            float v = acc[i];
#pragma unroll
            for (int off = 32; off; off >>= 1) v += __shfl_xor(v, off);
            if (lane == 0) Wt[(size_t)(N + i)*KP + k] = (f16)(v * s);
        }
    }
    if (blockIdx.x == 0){
        int wv = threadIdx.x >> 6;
        for (int i = wv; i < 2*H; i += 4){
            int h = (i < H) ? i : (i - H);
            const float* att = (i < H) ? (asrc + h*EMB) : (adst + h*EMB);
            float s = 0.f;
            for (int c = lane; c < EMB; c += 64) s += dvec[h*EMB + c] * att[c];
#pragma unroll
            for (int off = 32; off; off >>= 1) s += __shfl_xor(s, off);
            if (lane == 0) dvec[N + i] = s;
        }
    }
}

// ---------------- h0 (f16x4 stores) ----------------
__global__ void k_build_h(const float* __restrict__ x, const float* __restrict__ tW,
                          const float* __restrict__ tb, f16* __restrict__ h){
    int idx = blockIdx.x*256 + threadIdx.x;
    int total = NN*(EMBP/4);
    if (idx >= total) return;
    int n = idx / (EMBP/4);
    int c0 = (idx - n*(EMBP/4))*4;
    const float* xr = x + (size_t)n*772;
    f16x4 o;
#pragma unroll
    for (int j = 0; j < 4; j++){
        int c = c0 + j; float v;
        if (c < 768) v = xr[c];
        else if (c < EMB){
            int t = c - 768;
            v = tb[t] + xr[768]*tW[t] + xr[769]*tW[12+t] + xr[770]*tW[24+t] + xr[771]*tW[36+t];
        } else v = 0.f;
        o[j] = (f16)v;
    }
    *(f16x4*)(h + (size_t)n*EMBP + c0) = o;
}

// ---------------- CSR build ----------------
__global__ void k_deg(const int* __restrict__ ei, int* __restrict__ deg){
    int k = blockIdx.x*256 + threadIdx.x; if (k >= ELP) return;
    int d = (k < EE) ? ei[EE + k] : (k - EE);
    atomicAdd(&deg[d], 1);
}

// 20 nodes/thread local sum -> single 1024-scan -> write prefixes into rp AND cursor(deg, in place)
__global__ __launch_bounds__(1024) void k_scan(int* __restrict__ deg, int* __restrict__ rp){
    __shared__ int part[1024];
    int tid = threadIdx.x;
    int i0 = tid*20;
    int n = (i0 < NN) ? min(20, NN - i0) : 0;
    int s = 0;
    for (int k = 0; k < n; k++) s += deg[i0+k];
    part[tid] = s; __syncthreads();
    for (int off = 1; off < 1024; off <<= 1){
        int t = (tid >= off) ? part[tid-off] : 0;
        __syncthreads();
        part[tid] += t;
        __syncthreads();
    }
    int run = part[tid] - s;   // exclusive prefix
    for (int k = 0; k < n; k++){
        int d = deg[i0+k];
        rp[i0+k] = run;
        deg[i0+k] = run;       // cursor init
        run += d;
    }
    if (tid == 1023) rp[NN] = part[1023];
}

__global__ void k_fill(const int* __restrict__ ei, int* __restrict__ cursor, int* __restrict__ csrc){
    int k = blockIdx.x*256 + threadIdx.x; if (k >= ELP) return;
    int s, d;
    if (k < EE){ s = ei[k]; d = ei[EE + k]; } else { s = k - EE; d = s; }
    int pos = atomicAdd(&cursor[d], 1);
    csrc[pos] = s;
}

__global__ void k_grp(const int* __restrict__ batch, int* __restrict__ grp){
    int g = blockIdx.x*256 + threadIdx.x; if (g > NGR) return;
    int lo = 0, hi = NN;
    while (lo < hi){ int mid = (lo+hi)>>1; if (batch[mid] < g) lo = mid+1; else hi = mid; }
    grp[g] = lo;
}

// ------ MFMA f16 GEMM, XCD-pinned strips, BK=64, LDS-staged coalesced epilogue ------
__global__ __launch_bounds__(256) void k_gemm_mfma(const f16* __restrict__ A,
                                                   const f16* __restrict__ Bt,
                                                   const float* __restrict__ dvec,
                                                   f16* __restrict__ C,
                                                   float* __restrict__ a_sd,
                                                   int M, int N, int NB, int H,
                                                   int KP, int SN,
                                                   int Mtiles, int NT){
    int bid = blockIdx.x;
    int xcd = bid & 7;
    int j   = bid >> 3;
    int sl  = j / NT;
    int nt  = j - sl*NT;
    int mt  = sl*8 + xcd;
    if (mt >= Mtiles) return;
    int m0 = mt*128, n0 = nt*128;

    __shared__ f16 smem[128*136];   // K-loop: As=smem[0:8192), Bs=smem[8192:16384); epilogue: C tile 128x136
    f16* As = smem;
    f16* Bs = smem + 8192;
    int tid = threadIdx.x;
    int w = tid >> 6, lane = tid & 63;

    int lrow = lane >> 2;
    int lko  = (lane & 3) * 8;

    int i2a = w*2, i2b = w*2 + 1;
    const f16* gA0 = A  + (size_t)min(m0 + i2a*16 + lrow, M-1)*KP + lko;
    const f16* gA1 = A  + (size_t)min(m0 + i2b*16 + lrow, M-1)*KP + lko;
    const f16* gB0 = Bt + (size_t)min(n0 + i2a*16 + lrow, NB-1)*KP + lko;
    const f16* gB1 = Bt + (size_t)min(n0 + i2b*16 + lrow, NB-1)*KP + lko;
    f16* lA0 = &As[i2a*512]; f16* lA1 = &As[i2b*512];
    f16* lB0 = &Bs[i2a*512]; f16* lB1 = &Bs[i2b*512];

    f32x4 acc[4][4];
#pragma unroll
    for (int i = 0; i < 4; i++)
#pragma unroll
        for (int j2 = 0; j2 < 4; j2++) acc[i][j2] = (f32x4)0.f;

    int wm = (w & 1) * 64, wn = (w >> 1) * 64;
    int lq = lane >> 4, lm = lane & 15;

    for (int kk = 0; kk < KP; kk += 64){
        __syncthreads();
        async_ld16(gA0 + kk, lA0);
        async_ld16(gA1 + kk, lA1);
        async_ld16(gB0 + kk, lB0);
        async_ld16(gB1 + kk, lB1);
        async_ld16(gA0 + kk + 32, lA0 + 4096);
        async_ld16(gA1 + kk + 32, lA1 + 4096);
        async_ld16(gB0 + kk + 32, lB0 + 4096);
        async_ld16(gB1 + kk + 32, lB1 + 4096);
        __syncthreads();

#pragma unroll
        for (int half = 0; half < 2; half++){
            const f16* Ap = As + half*4096;
            const f16* Bp = Bs + half*4096;
            f16x8 aF[4], bF[4];
#pragma unroll
            for (int mi = 0; mi < 4; mi++)
                aF[mi] = *(const f16x8*)&Ap[(wm + mi*16 + lm)*32 + lq*8];
#pragma unroll
            for (int ni = 0; ni < 4; ni++)
                bF[ni] = *(const f16x8*)&Bp[(wn + ni*16 + lm)*32 + lq*8];
#pragma unroll
            for (int mi = 0; mi < 4; mi++)
#pragma unroll
                for (int ni = 0; ni < 4; ni++)
                    acc[mi][ni] = __builtin_amdgcn_mfma_f32_16x16x32_f16(aF[mi], bF[ni], acc[mi][ni], 0, 0, 0);
        }
    }

    // attention columns ([N,NB)) -> a_sd directly (registers only)
#pragma unroll
    for (int mi = 0; mi < 4; mi++){
#pragma unroll
        for (int ni = 0; ni < 4; ni++){
            int col = n0 + wn + ni*16 + lm;
            if (col >= N && col < NB){
                int jc = col - N;
                int idx = (jc < H) ? jc : (3 + jc - H);
                float dv = dvec[col];
                int rbase = m0 + wm + mi*16 + lq*4;
#pragma unroll
                for (int r = 0; r < 4; r++){
                    int row = rbase + r;
                    if (row < M) a_sd[(size_t)row*6 + idx] = acc[mi][ni][r] + dv;
                }
            }
        }
    }

    // stage C tile into LDS (stride 136 to spread banks), then bulk coalesced f16x8 stores
    if (n0 < N){
        __syncthreads();   // all waves done with As/Bs
#pragma unroll
        for (int mi = 0; mi < 4; mi++){
#pragma unroll
            for (int ni = 0; ni < 4; ni++){
                int col = wn + ni*16 + lm;
                int gcol = n0 + col;
                float dv = (gcol < N) ? dvec[gcol] : 0.f;
#pragma unroll
                for (int r = 0; r < 4; r++){
                    int row = wm + mi*16 + lq*4 + r;
                    smem[row*136 + col] = (f16)(acc[mi][ni][r] + dv);
                }
            }
        }
        __syncthreads();
        int ncols = min(128, N - n0);
#pragma unroll
        for (int it = 0; it < 8; it++){
            int ch = tid + it*256;          // 2048 chunks: row = ch/16, col-chunk = (ch%16)*8
            int row = ch >> 4, cc = (ch & 15)*8;
            int grow = m0 + row;
            if (grow < M && cc < ncols){
                if (cc + 8 <= ncols){
                    f16x8 v = *(f16x8*)&smem[row*136 + cc];
                    *(f16x8*)(C + (size_t)grow*SN + n0 + cc) = v;
                } else {
                    for (int jj = cc; jj < ncols; jj++)
                        C[(size_t)grow*SN + n0 + jj] = smem[row*136 + jj];
                }
            }
        }
    }
}

// ---- per-dst softmax + aggregation + bias + tanh: barrier-free, LDS-free, f16x8 ----
template<int H>
__global__ __launch_bounds__(256) void k_agg2(const f16* __restrict__ hp, const int* __restrict__ rp,
                                              const int* __restrict__ csrc, const float* __restrict__ a_sd,
                                              const float* __restrict__ bias,
                                              f16* __restrict__ y, int SP, int W){
    int n = blockIdx.x, tid = threadIdx.x, lane = tid & 63;
    int beg = rp[n], deg = rp[n+1] - beg;

    float adv[H];
#pragma unroll
    for (int h = 0; h < H; h++) adv[h] = a_sd[(size_t)n*6 + 3 + h];

    // pass 1: max
    float mx[H];
#pragma unroll
    for (int h = 0; h < H; h++) mx[h] = -1e30f;
    for (int base = 0; base < deg; base += 64){
        int e = base + lane;
        if (e < deg){
            int s = csrc[beg + e];
#pragma unroll
            for (int h = 0; h < H; h++){
                float t = a_sd[(size_t)s*6 + h] + adv[h];
                t = t > 0.f ? t : 0.2f*t;
                mx[h] = fmaxf(mx[h], t);
            }
        }
    }
#pragma unroll
    for (int off = 32; off; off >>= 1)
#pragma unroll
        for (int h = 0; h < H; h++) mx[h] = fmaxf(mx[h], __shfl_xor(mx[h], off));

    // pass 2: denom
    float dn[H];
#pragma unroll
    for (int h = 0; h < H; h++) dn[h] = 0.f;
    for (int base = 0; base < deg; base += 64){
        int e = base + lane;
        if (e < deg){
            int s = csrc[beg + e];
#pragma unroll
            for (int h = 0; h < H; h++){
                float t = a_sd[(size_t)s*6 + h] + adv[h];
                t = t > 0.f ? t : 0.2f*t;
                dn[h] += expf(t - mx[h]);
            }
        }
    }
#pragma unroll
    for (int off = 32; off; off >>= 1)
#pragma unroll
        for (int h = 0; h < H; h++) dn[h] += __shfl_xor(dn[h], off);
    float inv[H];
#pragma unroll
    for (int h = 0; h < H; h++) inv[h] = 1.f / (dn[h] + 1e-16f);

    // column groups: c = 2048*g + tid*8
    float acc[2][8];
#pragma unroll
    for (int g = 0; g < 2; g++)
#pragma unroll
        for (int j = 0; j < 8; j++) acc[g][j] = 0.f;
    int  cg[2];  cg[0] = tid*8; cg[1] = 2048 + tid*8;
    bool act[2]; act[0] = cg[0] < W; act[1] = cg[1] < W;
    int hlo[2], hhi[2], nsp[2];
#pragma unroll
    for (int g = 0; g < 2; g++){
        int c = cg[g];
        int hl = min(c / EMB, H-1);
        int hh = min((c+7) / EMB, H-1);
        hlo[g] = hl; hhi[g] = hh;
        nsp[g] = (hh > hl) ? (EMB*(hl+1) - c) : 8;
    }

    for (int base = 0; base < deg; base += 64){
        int cnt = min(64, deg - base);
        int sl = 0; float al[H];
        {
            int e = base + lane;
            if (e < deg){
                sl = csrc[beg + e];
#pragma unroll
                for (int h = 0; h < H; h++){
                    float t = a_sd[(size_t)sl*6 + h] + adv[h];
                    t = t > 0.f ? t : 0.2f*t;
                    al[h] = expf(t - mx[h]) * inv[h];
                }
            } else {
#pragma unroll
                for (int h = 0; h < H; h++) al[h] = 0.f;
            }
        }
#pragma unroll 4
        for (int e = 0; e < cnt; e++){
            int s = __shfl(sl, e);
            float a0 = __shfl(al[0], e);
            float a1 = (H==3) ? __shfl(al[1], e) : a0;
            float a2 = (H==3) ? __shfl(al[2], e) : a0;
            const f16* row = hp + (size_t)s*SP;
#pragma unroll
            for (int g = 0; g < 2; g++){
                if (act[g]){
                    f16x8 v = *(const f16x8*)(row + cg[g]);
                    float lo = (hlo[g]==0) ? a0 : (hlo[g]==1 ? a1 : a2);
                    float hi = (hhi[g]==0) ? a0 : (hhi[g]==1 ? a1 : a2);
#pragma unroll
                    for (int j = 0; j < 8; j++){
                        float alj = (j < nsp[g]) ? lo : hi;
                        acc[g][j] += alj * (float)v[j];
                    }
                }
            }
        }
    }

    // epilogue: bias + tanh + write (pad cols -> 0)
#pragma unroll
    for (int g = 0; g < 2; g++){
        int c = cg[g];
        if (c < SP){
            f16x8 o;
#pragma unroll
            for (int j = 0; j < 8; j++){
                float vv = (c + j < W) ? tanhf(acc[g][j] + bias[c+j]) : 0.f;
                o[j] = (f16)vv;
            }
            *(f16x8*)(y + (size_t)n*SP + c) = o;
        }
    }
}

// ---------------- BatchNorm stats: contiguous-row-range partials (no atomics) ----------------
__global__ void k_bnstat(const f16* __restrict__ y, float* __restrict__ ps,
                         float* __restrict__ pq, int W, int SP){
    int c0 = (blockIdx.x*256 + threadIdx.x)*4;
    if (c0 >= W) return;
    int slice = blockIdx.y;   // 0..127
    int r0 = (int)(((long long)NN*slice)/128);
    int r1 = (int)(((long long)NN*(slice+1))/128);
    float s[4] = {0,0,0,0}, q[4] = {0,0,0,0};
    for (int r = r0; r < r1; r++){
        f16x4 u = *(const f16x4*)(y + (size_t)r*SP + c0);
#pragma unroll
        for (int j = 0; j < 4; j++){ float v = (float)u[j]; s[j] += v; q[j] += v*v; }
    }
#pragma unroll
    for (int j = 0; j < 4; j++){
        ps[(size_t)slice*W3 + c0+j] = s[j];
        pq[(size_t)slice*W3 + c0+j] = q[j];
    }
}

// reduce partials; sc = istd*gamma, sh = beta - mu*istd*gamma; zero dvec for next layer
__global__ void k_bnfin(const float* __restrict__ ps, const float* __restrict__ pq,
                        const float* __restrict__ gamma, const float* __restrict__ beta,
                        float* __restrict__ sc, float* __restrict__ sh,
                        float* __restrict__ dvec, int W, int zn){
    int c = blockIdx.x*256 + threadIdx.x;
    if (c < W){
        float m = 0.f, q = 0.f;
        for (int s = 0; s < 128; s++){ m += ps[(size_t)s*W3 + c]; q += pq[(size_t)s*W3 + c]; }
        m *= (1.f/NN);
        float v = q * (1.f/NN) - m*m;
        float is = 1.f / sqrtf(v + 1e-5f);
        float g = gamma[c];
        sc[c] = is * g;
        sh[c] = beta[c] - m * is * g;
    }
    if (c < zn) dvec[c] = 0.f;
}

// ---------------- segmented pooling (raw y; BN folded into MLP) ----------------
__global__ void k_pool(const f16* __restrict__ h, const int* __restrict__ grp,
                       float* __restrict__ pooled){
    int g = blockIdx.x;
    int c = threadIdx.x*4;
    if (c >= EMB) return;
    int r0 = grp[g], r1 = grp[g+1];
    float s0=0.f, s1=0.f, s2=0.f, s3=0.f;
    for (int r = r0; r < r1; r++){
        f16x4 u = *(const f16x4*)(h + (size_t)r*EMBP + c);
        s0 += (float)u[0]; s1 += (float)u[1]; s2 += (float)u[2]; s3 += (float)u[3];
    }
    pooled[g*EMB + c] = s0; pooled[g*EMB + c+1] = s1;
    pooled[g*EMB + c+2] = s2; pooled[g*EMB + c+3] = s3;
}

__global__ __launch_bounds__(256) void k_mlp(const float* __restrict__ pooled, const int* __restrict__ grp,
                                             const float* __restrict__ sc, const float* __restrict__ sh,
                                             const float* __restrict__ W1, const float* __restrict__ b1,
                                             const float* __restrict__ W2, const float* __restrict__ b2,
                                             float* __restrict__ out){
    __shared__ float p[EMB];
    __shared__ float hid[128];
    int g = blockIdx.x, tid = threadIdx.x;
    int cnt = grp[g+1] - grp[g];
    float ic = 1.f / fmaxf((float)cnt, 1.f);
    for (int c = tid; c < EMB; c += 256){
        float v = pooled[g*EMB + c] * ic * sc[c] + sh[c];   // BN(mean) — affine commutes with mean
        p[c] = v > 0.f ? v : 0.f;
    }
    __syncthreads();
    if (tid < 128){
        float s = b1[tid];
        for (int k = 0; k < EMB; k++) s += p[k] * W1[k*128 + tid];
        hid[tid] = tanhf(s);
    }
    __syncthreads();
    if (tid < 64){
        float s = b2[tid];
        for (int k = 0; k < 128; k++) s += hid[k] * W2[k*64 + tid];
        out[g*64 + tid] = s;
    }
}

// ---------------- launch ----------------
extern "C" void kernel_launch(void* const* d_in, const int* in_sizes, int n_in,
                              void* d_out, int out_size, void* d_ws, size_t ws_size,
                              hipStream_t stream) {
    (void)in_sizes; (void)n_in; (void)out_size;
    const float* x    = (const float*)d_in[0];
    const int*   ei   = (const int*)  d_in[1];
    const int*   batch= (const int*)  d_in[2];
    const float* tW   = (const float*)d_in[3];
    const float* tb   = (const float*)d_in[4];
    const float* W0   = (const float*)d_in[5];
    const float* as0  = (const float*)d_in[6];
    const float* ad0  = (const float*)d_in[7];
    const float* b0   = (const float*)d_in[8];
    const float* g0   = (const float*)d_in[9];
    const float* be0  = (const float*)d_in[10];
    const float* W1   = (const float*)d_in[11];
    const float* as1  = (const float*)d_in[12];
    const float* ad1  = (const float*)d_in[13];
    const float* b1   = (const float*)d_in[14];
    const float* g1   = (const float*)d_in[15];
    const float* be1  = (const float*)d_in[16];
    const float* W2   = (const float*)d_in[17];
    const float* as2  = (const float*)d_in[18];
    const float* ad2  = (const float*)d_in[19];
    const float* b2   = (const float*)d_in[20];
    const float* g2   = (const float*)d_in[21];
    const float* be2  = (const float*)d_in[22];
    const float* mW1  = (const float*)d_in[23];
    const float* mb1  = (const float*)d_in[24];
    const float* mW2  = (const float*)d_in[25];
    const float* mb2  = (const float*)d_in[26];
    float* outp = (float*)d_out;

    size_t off = 0;
    auto carve = [&](size_t bytes) -> void* {
        void* p = (char*)d_ws + off;
        off = (off + bytes + 255) & ~(size_t)255;
        return p;
    };
    f16* big1 = (f16*)carve((size_t)NN*W3P*2);          // h / y buffers
    f16* big2 = (f16*)carve((size_t)NN*W3P*2);          // hp buffer
    f16* Wt   = (f16*)carve((size_t)NZ*W3P*2);          // transposed weights + attention rows
    float* a_sd  = (float*)carve((size_t)NN*6*4);       // [n][a_s(3), a_d(3)]
    float* psum  = (float*)carve((size_t)128*W3*4);     // bnstat partials
    float* psq   = (float*)carve((size_t)128*W3*4);
    float* sc    = (float*)carve((size_t)W3*4);
    float* sh    = (float*)carve((size_t)W3*4);
    float* dvec  = (float*)carve((size_t)NZ*4);
    float* pooled= (float*)carve((size_t)NGR*EMB*4);
    int*   grp   = (int*)carve((size_t)(NGR+1)*4);
    int*   deg   = (int*)carve((size_t)NN*4);           // reused as cursor
    int*   rp    = (int*)carve((size_t)(NN+1)*4);
    int*   csrc  = (int*)carve((size_t)ELP*4);

    if (ws_size < off) return;

    // CSR build
    k_zero_i32<<<cdiv_i(NN,256),256,0,stream>>>(deg, NN);
    k_deg<<<cdiv_i(ELP,256),256,0,stream>>>(ei, deg);
    k_scan<<<1,1024,0,stream>>>(deg, rp);
    k_fill<<<cdiv_i(ELP,256),256,0,stream>>>(ei, deg, csrc);
    k_grp<<<1,256,0,stream>>>(batch, grp);

    // h0 + initial dvec zero (layer 0 has no BN fold)
    k_build_h<<<cdiv_i((long long)NN*(EMBP/4),256),256,0,stream>>>(x, tW, tb, big1);
    k_zero_f32<<<cdiv_i(NZ,256),256,0,stream>>>(dvec, NZ);

    struct Layer { const float* W; const float* as; const float* ad; const float* b;
                   const float* g; const float* be; int H; int K; int KP; };
    Layer layers[3] = {
        {W0, as0, ad0, b0, g0, be0, 3, EMB, EMBP},
        {W1, as1, ad1, b1, g1, be1, 3, W3,  W3P },
        {W2, as2, ad2, b2, g2, be2, 1, W3,  W3P },
    };

    for (int L = 0; L < 3; L++){
        Layer& ly = layers[L];
        int Wout  = ly.H * EMB;                 // 2340 / 2340 / 780
        int NB    = Wout + 2*ly.H;              // + attention columns
        int SPout = (Wout == W3) ? W3P : EMBP;  // 2368 / 2368 / 832
        const float* scale = (L == 0) ? nullptr : sc;
        const float* shift = (L == 0) ? nullptr : sh;

        // Wt rows [0,Wout): scaled W^T (+ fused dvec accumulation); rows [Wout,NB): att fold
        dim3 tg(cdiv_i(Wout,32), cdiv_i(ly.KP,32));
        k_transpose<<<tg, dim3(32,8), 0, stream>>>(ly.W, Wt, scale, shift, dvec, ly.K, Wout, ly.KP);
        k_wvec<<<cdiv_i(ly.K,4),256,0,stream>>>(ly.W, ly.as, ly.ad, scale, Wt, dvec, ly.K, Wout, ly.KP, ly.H);

        // hp (+ a_s/a_d) = BN(h) @ [W | w_att] via f16 MFMA, XCD-pinned strips, BK=64
        int Mtiles = cdiv_i(NN,128), NT = cdiv_i(NB,128);
        int nb = ((Mtiles+7)/8)*8*NT;
        k_gemm_mfma<<<nb, 256, 0, stream>>>(big1, Wt, dvec, big2, a_sd,
                                            NN, Wout, NB, ly.H, ly.KP, SPout, Mtiles, NT);

        // softmax + aggregate + bias + tanh -> big1 (pre-BN y, pads zeroed)
        if (ly.H == 3)
            k_agg2<3><<<NN,256,0,stream>>>(big2, rp, csrc, a_sd, ly.b, big1, SPout, Wout);
        else
            k_agg2<1><<<NN,256,0,stream>>>(big2, rp, csrc, a_sd, ly.b, big1, SPout, Wout);

        // BN stats + fold coefficients (+ zero dvec for next layer)
        dim3 gs(cdiv_i(Wout/4,256), 128);
        k_bnstat<<<gs,256,0,stream>>>(big1, psum, psq, Wout, SPout);
        int zn = (L < 2) ? NZ : 0;
        k_bnfin<<<cdiv_i(Wout,256),256,0,stream>>>(psum, psq, ly.g, ly.be, sc, sh, dvec, Wout, zn);
    }

    // segmented pooling (raw y) + MLP (applies final BN affine on pooled means)
    k_pool<<<NGR,256,0,stream>>>(big1, grp, pooled);
    k_mlp<<<NGR,256,0,stream>>>(pooled, grp, sc, sh, mW1, mb1, mW2, mb2, outp);
}